// Round 5
// baseline (634.230 us; speedup 1.0000x reference)
//
#include <hip/hip_runtime.h>

#define HD 64
#define NNODE 50000
#define NEDGE 100000
#define NGR 500
#define NPG 100      // nodes per graph (sorted, contiguous, equal size)
#define EPAD 100352  // 1568 * 64
#define NCH 66       // K chunks of 128 (K_total = 8448 = 132 ku * 64)

typedef _Float16 f16;
typedef _Float16 f16x2 __attribute__((ext_vector_type(2)));
typedef _Float16 f16x8 __attribute__((ext_vector_type(8)));
typedef float f32x4 __attribute__((ext_vector_type(4)));
typedef float f32x16 __attribute__((ext_vector_type(16)));

__device__ __forceinline__ float sigmoidf_(float x) { return 1.f / (1.f + __expf(-x)); }

// ---------------- K1: h = relu(nfeat @ lin0_w + b), [N,32]@[32,64] ----------------
__global__ void k_node_init(const float* __restrict__ nfeat, const float* __restrict__ w,
                            const float* __restrict__ b, float* __restrict__ h) {
    int idx = blockIdx.x * 256 + threadIdx.x;
    int n = idx >> 6, o = idx & 63;
    if (n >= NNODE) return;
    const float* nf = nfeat + n * 32;
    float acc = b[o];
#pragma unroll
    for (int i = 0; i < 32; i++) acc += nf[i] * w[i * 64 + o];
    h[idx] = fmaxf(acc, 0.f);
}

// ---------------- K2: uP[c][e] = (u[e][2c], u[e][2c+1]); u = relu(efeat@ew1+eb1), col128=1 ----
__global__ __launch_bounds__(256) void k_edge_mlp(const float* __restrict__ efeat,
                                                  const float* __restrict__ w,
                                                  const float* __restrict__ b,
                                                  f16x2* __restrict__ uP) {
    __shared__ float sef[256 * 5];
    __shared__ float sw[5 * 128];
    __shared__ float sb[128];
    int t = threadIdx.x;
    int e0 = blockIdx.x * 256;
    for (int idx = t; idx < 1280; idx += 256) {
        int gi = e0 * 5 + idx;
        sef[idx] = (gi < NEDGE * 5) ? efeat[gi] : 0.f;
    }
    for (int idx = t; idx < 640; idx += 256) sw[idx] = w[idx];
    if (t < 128) sb[t] = b[t];
    __syncthreads();
    int e = e0 + t;
    bool valid = e < NEDGE;
    float ef[5];
#pragma unroll
    for (int i = 0; i < 5; i++) ef[i] = sef[t * 5 + i];
#pragma unroll 2
    for (int c = 0; c < NCH; c++) {
        float v[2];
#pragma unroll
        for (int s = 0; s < 2; s++) {
            int kk = 2 * c + s;
            float acc = 0.f;
            if (kk < 128) {
                acc = sb[kk];
#pragma unroll
                for (int i = 0; i < 5; i++) acc += ef[i] * sw[i * 128 + kk];
                acc = fmaxf(acc, 0.f);
            } else if (kk == 128) {
                acc = 1.f;
            }
            v[s] = valid ? acc : 0.f;
        }
        f16x2 pv;
        pv[0] = (f16)v[0];
        pv[1] = (f16)v[1];
        uP[(size_t)c * EPAD + e] = pv;
    }
}

// ---------------- K3: pack W2ext (= [ew2; eb2; zeros], [8448][64]) into 32x32x16 B-frag order
// f16x8 index F = c*1024 + ch*512 + ks*64 + lane; value[q] = W2ext[c*128 + ks*16 + (l>>5)*8 + q][ch*32 + (l&31)]
__global__ void k_pack_b(const float* __restrict__ ew2, const float* __restrict__ eb2,
                         f16* __restrict__ w2hp) {
    int idx = blockIdx.x * 256 + threadIdx.x;
    if (idx >= 540672) return;  // 66*1024 f16x8 * 8
    int q = idx & 7;
    int F = idx >> 3;
    int l = F & 63;
    int ks = (F >> 6) & 7;
    int ch = (F >> 9) & 1;
    int c = F >> 10;
    int kg = c * 128 + ks * 16 + (l >> 5) * 8 + q;
    int n = ch * 32 + (l & 31);
    float v = 0.f;
    if (kg < 8192) v = ew2[kg * 64 + n];          // ew2 flat == W2flat[kg][n]
    else if (kg < 8256) v = eb2[(kg - 8192) * 64 + n];
    w2hp[idx] = (f16)v;
}

// ---------------- K3b: GRU weights -> f16, gate-col permuted, [192][64] ----------------
__global__ void k_prep_gru2(const float* __restrict__ wih, const float* __restrict__ whh,
                            f16* __restrict__ B1, f16* __restrict__ B2) {
    int idx = blockIdx.x * 256 + threadIdx.x;
    if (idx >= 12288) return;
    int cp = idx >> 6, k = idx & 63;
    int w = cp / 48, rem = cp % 48;
    int tg = rem >> 4, cc = rem & 15;
    int orow = tg * 64 + w * 16 + cc;
    B1[idx] = (f16)wih[orow * 64 + k];
    B2[idx] = (f16)whh[orow * 64 + k];
}

// ---------------- K3c: generic small f32 transpose (LSTM weights) ----------------
__global__ void k_transpose_f32(const float* __restrict__ in, float* __restrict__ outp,
                                int rows, int cols) {
    int idx = blockIdx.x * 256 + threadIdx.x;
    if (idx >= rows * cols) return;
    int r = idx / cols, c = idx - r * cols;
    outp[c * rows + r] = in[idx];
}

// ---------------- padded index arrays ----------------
__global__ void k_pad_idx(const int* __restrict__ src, const int* __restrict__ dst,
                          int* __restrict__ srcP, int* __restrict__ dstP) {
    int e = blockIdx.x * 256 + threadIdx.x;
    if (e >= EPAD) return;
    srcP[e] = (e < NEDGE) ? src[e] : 0;
    dstP[e] = (e < NEDGE) ? dst[e] : -1;
}

// ---------------- degree ----------------
__global__ void k_deg_count(const int* __restrict__ dst, int* __restrict__ cnt) {
    int e = blockIdx.x * 256 + threadIdx.x;
    if (e < NEDGE) atomicAdd(&cnt[dst[e]], 1);
}
__global__ void k_deg_inv(const int* __restrict__ cnt, float* __restrict__ dinv) {
    int n = blockIdx.x * 256 + threadIdx.x;
    if (n < NNODE) dinv[n] = 1.f / (float)max(cnt[n], 1);
}

// ---------------- K6: fused msg + scatter, LDS-free, 32x32x16 MFMA ----------------
// One wave per block; wave = 64 edges x 32 cols (2 M-tiles of 32, 1 N-tile, ch half).
// B single-buffered from L2 (1MB, hot); u prefetched 1 chunk ahead; acc in AGPRs.
__global__ __launch_bounds__(64) void k_msg_fused(
    const float* __restrict__ h, const f16x2* __restrict__ uP, const f16* __restrict__ w2hp,
    const int* __restrict__ srcP, const int* __restrict__ dstP, float* __restrict__ agg) {
    int l = threadIdx.x;
    int wid = blockIdx.x;
    int eb = (wid >> 1) * 64;  // edge base
    int ch = wid & 1;          // column half (32 cols)
    int lm = l & 31, hi = l >> 5;
    // A-side x fragments: xf[i][h4][q] = f16(h[src[eb+i*32+lm]][h4*16 + hi*8 + q])
    f16x8 xf[2][4];
#pragma unroll
    for (int i = 0; i < 2; i++) {
        const float* xb = h + (size_t)srcP[eb + i * 32 + lm] * 64;
#pragma unroll
        for (int h4 = 0; h4 < 4; h4++) {
            float4 v0 = *(const float4*)(xb + h4 * 16 + hi * 8);
            float4 v1 = *(const float4*)(xb + h4 * 16 + hi * 8 + 4);
            f16x8 xv;
            xv[0] = (f16)v0.x; xv[1] = (f16)v0.y; xv[2] = (f16)v0.z; xv[3] = (f16)v0.w;
            xv[4] = (f16)v1.x; xv[5] = (f16)v1.y; xv[6] = (f16)v1.z; xv[7] = (f16)v1.w;
            xf[i][h4] = xv;
        }
    }
    const f16x8* gBp = (const f16x8*)w2hp + ch * 512 + l;
    const f16x2* up0 = uP + eb + lm;
    const f16x2* up1 = up0 + 32;
    f32x16 acc0, acc1;
#pragma unroll
    for (int r = 0; r < 16; r++) { acc0[r] = 0.f; acc1[r] = 0.f; }
    f16x2 uA0 = up0[0], uA1 = up1[0];
    up0 += EPAD; up1 += EPAD;
    for (int c = 0; c < NCH; c++) {
        // load current chunk's 8 B fragments (L1/L2-resident stream)
        const f16x8* bb = gBp + (size_t)c * 1024;
        f16x8 bf[8];
#pragma unroll
        for (int ks = 0; ks < 8; ks++) bf[ks] = bb[ks * 64];
        // prefetch next chunk's u
        f16x2 uB0, uB1;
        if (c + 1 < NCH) { uB0 = up0[0]; uB1 = up1[0]; up0 += EPAD; up1 += EPAD; }
#pragma unroll
        for (int ks = 0; ks < 8; ks++) {
            f16 u0 = uA0[ks >> 2], u1 = uA1[ks >> 2];
            f16x8 av0 = xf[0][ks & 3] * u0;
            f16x8 av1 = xf[1][ks & 3] * u1;
            acc0 = __builtin_amdgcn_mfma_f32_32x32x16_f16(av0, bf[ks], acc0, 0, 0, 0);
            acc1 = __builtin_amdgcn_mfma_f32_32x32x16_f16(av1, bf[ks], acc1, 0, 0, 0);
        }
        uA0 = uB0; uA1 = uB1;
    }
    // scatter: C layout col = lane&31, row = (reg&3) + 8*(reg>>2) + 4*(lane>>5)
#pragma unroll
    for (int i = 0; i < 2; i++) {
        int rbase = eb + i * 32 + 4 * hi;
#pragma unroll
        for (int b = 0; b < 4; b++) {
            int4 d4 = *(const int4*)(dstP + rbase + 8 * b);
#pragma unroll
            for (int rr = 0; rr < 4; rr++) {
                int d = (rr == 0) ? d4.x : (rr == 1) ? d4.y : (rr == 2) ? d4.z : d4.w;
                float v = (i == 0) ? acc0[b * 4 + rr] : acc1[b * 4 + rr];
                if (d >= 0) atomicAdd(agg + (size_t)d * 64 + ch * 32 + lm, v);
            }
        }
    }
}

// ---------------- K7: GRU via MFMA, 64 nodes/block; weights direct from L1/L2 ----------------
#define GWP 72
__global__ __launch_bounds__(256) void k_gru2(const float* __restrict__ agg,
                                              const float* __restrict__ dinv,
                                              const float* __restrict__ convb,
                                              const f16* __restrict__ B1g,
                                              const f16* __restrict__ B2g,
                                              const float* __restrict__ bih,
                                              const float* __restrict__ bhh,
                                              float* __restrict__ h) {
    __shared__ f16 sM[64 * GWP];
    __shared__ f16 sH[64 * GWP];
    int t = threadIdx.x;
    int nb = blockIdx.x * 64;
    int w = t >> 6, l = t & 63, lr = l & 15, lg = l >> 4;
    // B fragments straight from global (48KB, L1/L2-hot across blocks)
    f16x8 b1[2][3], b2[2][3];
#pragma unroll
    for (int kk = 0; kk < 2; kk++)
#pragma unroll
        for (int j = 0; j < 3; j++) {
            size_t off = (size_t)(w * 48 + j * 16 + lr) * 64 + kk * 32 + lg * 8;
            b1[kk][j] = *(const f16x8*)(B1g + off);
            b2[kk][j] = *(const f16x8*)(B2g + off);
        }
#pragma unroll
    for (int it = 0; it < 16; it++) {
        int idx = t + 256 * it;
        int node = idx >> 6, k = idx & 63;
        int gn = nb + node;
        float mv = 0.f, hv = 0.f;
        if (gn < NNODE) {
            mv = fmaxf(agg[(size_t)gn * 64 + k] * dinv[gn] + convb[k], 0.f);
            hv = h[(size_t)gn * 64 + k];
        }
        sM[node * GWP + k] = (f16)mv;
        sH[node * GWP + k] = (f16)hv;
    }
    __syncthreads();
    f32x4 aih[4][3], ahh[4][3];
#pragma unroll
    for (int i = 0; i < 4; i++)
#pragma unroll
        for (int j = 0; j < 3; j++) {
            aih[i][j] = (f32x4){0.f, 0.f, 0.f, 0.f};
            ahh[i][j] = (f32x4){0.f, 0.f, 0.f, 0.f};
        }
#pragma unroll
    for (int kk = 0; kk < 2; kk++) {
        f16x8 am[4], ah[4];
#pragma unroll
        for (int i = 0; i < 4; i++) {
            am[i] = *(const f16x8*)(sM + (i * 16 + lr) * GWP + kk * 32 + lg * 8);
            ah[i] = *(const f16x8*)(sH + (i * 16 + lr) * GWP + kk * 32 + lg * 8);
        }
#pragma unroll
        for (int i = 0; i < 4; i++)
#pragma unroll
            for (int j = 0; j < 3; j++) {
                aih[i][j] = __builtin_amdgcn_mfma_f32_16x16x32_f16(am[i], b1[kk][j], aih[i][j], 0, 0, 0);
                ahh[i][j] = __builtin_amdgcn_mfma_f32_16x16x32_f16(ah[i], b2[kk][j], ahh[i][j], 0, 0, 0);
            }
    }
    float bi0 = bih[0 * 64 + w * 16 + lr], bh0 = bhh[0 * 64 + w * 16 + lr];
    float bi1 = bih[1 * 64 + w * 16 + lr], bh1 = bhh[1 * 64 + w * 16 + lr];
    float bi2 = bih[2 * 64 + w * 16 + lr], bh2 = bhh[2 * 64 + w * 16 + lr];
#pragma unroll
    for (int i = 0; i < 4; i++)
#pragma unroll
        for (int r = 0; r < 4; r++) {
            int node = i * 16 + lg * 4 + r;
            int gn = nb + node;
            if (gn >= NNODE) continue;
            float rg = sigmoidf_(aih[i][0][r] + bi0 + ahh[i][0][r] + bh0);
            float z = sigmoidf_(aih[i][1][r] + bi1 + ahh[i][1][r] + bh1);
            float nn = tanhf(aih[i][2][r] + bi2 + rg * (ahh[i][2][r] + bh2));
            size_t off = (size_t)gn * 64 + w * 16 + lr;
            float hold = h[off];
            h[off] = (1.f - z) * nn + z * hold;
        }
}

// ---------------- K8: fused Set2Set (3x LSTM + attention) + final MLP, block per graph ----
#define FP 68
__global__ __launch_bounds__(256) void k_s2s(const float* __restrict__ feat,
                                             const float* __restrict__ wihT,
                                             const float* __restrict__ whhT,
                                             const float* __restrict__ lbih,
                                             const float* __restrict__ lbhh,
                                             const float* __restrict__ fc1w,
                                             const float* __restrict__ fc1b,
                                             const float* __restrict__ fc2w,
                                             const float* __restrict__ fc2b,
                                             float* __restrict__ out) {
    __shared__ float sf[NPG * FP];
    __shared__ float sq[128];   // q_star = [q, readout]
    __shared__ float sh[64], scc[64];
    __shared__ float sg[256];
    __shared__ float se[NPG];
    __shared__ float red[2];
    int g = blockIdx.x, t = threadIdx.x;
    const float* fb = feat + (size_t)g * NPG * 64;
    for (int idx = t; idx < NPG * 64; idx += 256)
        sf[(idx >> 6) * FP + (idx & 63)] = fb[idx];
    if (t < 128) sq[t] = 0.f;
    if (t >= 128 && t < 192) { sh[t - 128] = 0.f; scc[t - 128] = 0.f; }
    __syncthreads();
    for (int it = 0; it < 3; it++) {
        // LSTM gates: all 256 threads, one gate each
        float gate = lbih[t] + lbhh[t];
#pragma unroll 8
        for (int i = 0; i < 128; i++) gate += sq[i] * wihT[i * 256 + t];
#pragma unroll 8
        for (int i = 0; i < 64; i++) gate += sh[i] * whhT[i * 256 + t];
        sg[t] = gate;
        __syncthreads();
        if (t < 64) {
            float ig = sigmoidf_(sg[t]);
            float fg = sigmoidf_(sg[64 + t]);
            float gg = tanhf(sg[128 + t]);
            float og = sigmoidf_(sg[192 + t]);
            float c = fg * scc[t] + ig * gg;
            scc[t] = c;
            float hv = og * tanhf(c);
            sh[t] = hv;
            sq[t] = hv;  // q part of q_star
        }
        __syncthreads();
        // attention scores
        if (t < NPG) {
            float e = 0.f;
#pragma unroll 8
            for (int o = 0; o < 64; o++) e += sf[t * FP + o] * sh[o];
            se[t] = e;
        }
        __syncthreads();
        if (t < 64) {
            float m = -1e30f;
            for (int i2 = t; i2 < NPG; i2 += 64) m = fmaxf(m, se[i2]);
            for (int d = 32; d; d >>= 1) m = fmaxf(m, __shfl_down(m, d));
            if (t == 0) red[0] = m;
        }
        __syncthreads();
        float emax = red[0];
        if (t < NPG) se[t] = __expf(se[t] - emax);
        __syncthreads();
        if (t < 64) {
            float s = 0.f;
            for (int i2 = t; i2 < NPG; i2 += 64) s += se[i2];
            for (int d = 32; d; d >>= 1) s += __shfl_down(s, d);
            if (t == 0) red[1] = s;
        }
        __syncthreads();
        if (t < 64) {
            float dnv = 1.f / red[1];
            float r = 0.f;
#pragma unroll 4
            for (int n = 0; n < NPG; n++) r += se[n] * sf[n * FP + t];
            sq[64 + t] = r * dnv;
        }
        __syncthreads();
    }
    // final MLP: relu(q_star@fc1+b1)@fc2+b2
    if (t < 64) {
        float hsum = fc1b[t];
#pragma unroll 8
        for (int i = 0; i < 128; i++) hsum += sq[i] * fc1w[i * 64 + t];
        float p = fmaxf(hsum, 0.f) * fc2w[t];
        for (int d = 32; d; d >>= 1) p += __shfl_down(p, d);
        if (t == 0) out[g] = p + fc2b[0];
    }
}

extern "C" void kernel_launch(void* const* d_in, const int* in_sizes, int n_in,
                              void* d_out, int out_size, void* d_ws, size_t ws_size,
                              hipStream_t stream) {
    const float* nfeat = (const float*)d_in[0];
    const float* efeat = (const float*)d_in[1];
    const float* lin0_w = (const float*)d_in[2];
    const float* lin0_b = (const float*)d_in[3];
    const float* ew1 = (const float*)d_in[4];
    const float* eb1 = (const float*)d_in[5];
    const float* ew2 = (const float*)d_in[6];
    const float* eb2 = (const float*)d_in[7];
    const float* convb = (const float*)d_in[8];
    const float* gwih = (const float*)d_in[9];
    const float* gwhh = (const float*)d_in[10];
    const float* gbih = (const float*)d_in[11];
    const float* gbhh = (const float*)d_in[12];
    const float* lwih = (const float*)d_in[13];
    const float* lwhh = (const float*)d_in[14];
    const float* lbih = (const float*)d_in[15];
    const float* lbhh = (const float*)d_in[16];
    const float* fc1w = (const float*)d_in[17];
    const float* fc1b = (const float*)d_in[18];
    const float* fc2w = (const float*)d_in[19];
    const float* fc2b = (const float*)d_in[20];
    const int* src = (const int*)d_in[21];
    const int* dst = (const int*)d_in[22];
    float* out = (float*)d_out;

    char* p = (char*)d_ws;
    auto alloc = [&](size_t bytes) {
        char* q = p;
        p += (bytes + 255) & ~(size_t)255;
        return q;
    };
    f16x2* uP = (f16x2*)alloc((size_t)NCH * EPAD * 4);      // 26.5 MB
    f16* w2hp = (f16*)alloc((size_t)540672 * 2);            // 1.08 MB
    float* h = (float*)alloc((size_t)NNODE * 64 * 4);       // 12.8 MB
    float* agg = (float*)alloc((size_t)NNODE * 64 * 4);     // 12.8 MB
    int* cnt = (int*)alloc((size_t)NNODE * 4);
    float* dinv = (float*)alloc((size_t)NNODE * 4);
    float* lwihT = (float*)alloc((size_t)128 * 256 * 4);
    float* lwhhT = (float*)alloc((size_t)64 * 256 * 4);
    f16* gB1 = (f16*)alloc((size_t)12288 * 2);
    f16* gB2 = (f16*)alloc((size_t)12288 * 2);
    int* srcP = (int*)alloc((size_t)EPAD * 4);
    int* dstP = (int*)alloc((size_t)EPAD * 4);
    if ((size_t)(p - (char*)d_ws) > ws_size) return;  // ~56 MB total

    hipMemsetAsync(cnt, 0, (size_t)NNODE * 4, stream);

    k_node_init<<<(NNODE * 64) / 256, 256, 0, stream>>>(nfeat, lin0_w, lin0_b, h);
    k_edge_mlp<<<EPAD / 256, 256, 0, stream>>>(efeat, ew1, eb1, uP);
    k_pack_b<<<(540672 + 255) / 256, 256, 0, stream>>>(ew2, eb2, w2hp);
    k_prep_gru2<<<48, 256, 0, stream>>>(gwih, gwhh, gB1, gB2);
    k_transpose_f32<<<(256 * 128 + 255) / 256, 256, 0, stream>>>(lwih, lwihT, 256, 128);
    k_transpose_f32<<<(256 * 64 + 255) / 256, 256, 0, stream>>>(lwhh, lwhhT, 256, 64);
    k_pad_idx<<<EPAD / 256, 256, 0, stream>>>(src, dst, srcP, dstP);
    k_deg_count<<<(NEDGE + 255) / 256, 256, 0, stream>>>(dst, cnt);
    k_deg_inv<<<(NNODE + 255) / 256, 256, 0, stream>>>(cnt, dinv);

    for (int it = 0; it < 3; it++) {
        hipMemsetAsync(agg, 0, (size_t)NNODE * 64 * 4, stream);
        k_msg_fused<<<(EPAD / 64) * 2, 64, 0, stream>>>(h, uP, w2hp, srcP, dstP, agg);
        k_gru2<<<(NNODE + 63) / 64, 256, 0, stream>>>(agg, dinv, convb, gB1, gB2, gbih, gbhh, h);
    }
    k_s2s<<<NGR, 256, 0, stream>>>(h, lwihT, lwhhT, lbih, lbhh, fc1w, fc1b, fc2w, fc2b, out);
}

// Round 6
// 557.882 us; speedup vs baseline: 1.1369x; 1.1369x over previous
//
#include <hip/hip_runtime.h>

#define HD 64
#define NNODE 50000
#define NEDGE 100000
#define NGR 500
#define NPG 100      // nodes per graph (sorted, contiguous, equal size)
#define EPAD 100352  // 1568 * 64
#define NCH 66       // B chunks of K=128 packed (we use 0..64; 64 = bias rows)

typedef _Float16 f16;
typedef _Float16 f16x2 __attribute__((ext_vector_type(2)));
typedef _Float16 f16x8 __attribute__((ext_vector_type(8)));
typedef float f32x4 __attribute__((ext_vector_type(4)));
typedef float f32x16 __attribute__((ext_vector_type(16)));

__device__ __forceinline__ float sigmoidf_(float x) { return 1.f / (1.f + __expf(-x)); }

// ---------------- K1: h = relu(nfeat @ lin0_w + b), [N,32]@[32,64] ----------------
__global__ void k_node_init(const float* __restrict__ nfeat, const float* __restrict__ w,
                            const float* __restrict__ b, float* __restrict__ h) {
    int idx = blockIdx.x * 256 + threadIdx.x;
    int n = idx >> 6, o = idx & 63;
    if (n >= NNODE) return;
    const float* nf = nfeat + n * 32;
    float acc = b[o];
#pragma unroll
    for (int i = 0; i < 32; i++) acc += nf[i] * w[i * 64 + o];
    h[idx] = fmaxf(acc, 0.f);
}

// ---------------- K2: uE[e][0:128] = f16(relu(efeat@ew1+eb1)), 256B/edge ----------------
// thread = (edge, 16-k group): 8 threads per edge, two f16x8 stores each.
__global__ __launch_bounds__(256) void k_edge_mlp(const float* __restrict__ efeat,
                                                  const float* __restrict__ w,
                                                  const float* __restrict__ b,
                                                  f16* __restrict__ uE) {
    __shared__ float sw[5 * 128];
    __shared__ float sb[128];
    int t = threadIdx.x;
    for (int idx = t; idx < 640; idx += 256) sw[idx] = w[idx];
    if (t < 128) sb[t] = b[t];
    __syncthreads();
    int idx = blockIdx.x * 256 + t;
    int e = idx >> 3, grp = idx & 7;
    if (e >= EPAD) return;
    bool valid = e < NEDGE;
    float ef[5];
#pragma unroll
    for (int i = 0; i < 5; i++) ef[i] = valid ? efeat[e * 5 + i] : 0.f;
    f16x8 v0, v1;
#pragma unroll
    for (int s = 0; s < 8; s++) {
        int k = grp * 16 + s;
        float acc = sb[k];
#pragma unroll
        for (int i = 0; i < 5; i++) acc += ef[i] * sw[i * 128 + k];
        v0[s] = valid ? (f16)fmaxf(acc, 0.f) : (f16)0.f;
    }
#pragma unroll
    for (int s = 0; s < 8; s++) {
        int k = grp * 16 + 8 + s;
        float acc = sb[k];
#pragma unroll
        for (int i = 0; i < 5; i++) acc += ef[i] * sw[i * 128 + k];
        v1[s] = valid ? (f16)fmaxf(acc, 0.f) : (f16)0.f;
    }
    *(f16x8*)(uE + (size_t)e * 128 + grp * 16) = v0;
    *(f16x8*)(uE + (size_t)e * 128 + grp * 16 + 8) = v1;
}

// ---------------- K3: pack W2ext (= [ew2; eb2; zeros], [8448][64]) into 32x32x16 B-frag order
// f16x8 index F = c*1024 + ch*512 + ks*64 + lane; value[q] = W2ext[c*128 + ks*16 + (l>>5)*8 + q][ch*32 + (l&31)]
__global__ void k_pack_b(const float* __restrict__ ew2, const float* __restrict__ eb2,
                         f16* __restrict__ w2hp) {
    int idx = blockIdx.x * 256 + threadIdx.x;
    if (idx >= 540672) return;  // 66*1024 f16x8 * 8
    int q = idx & 7;
    int F = idx >> 3;
    int l = F & 63;
    int ks = (F >> 6) & 7;
    int ch = (F >> 9) & 1;
    int c = F >> 10;
    int kg = c * 128 + ks * 16 + (l >> 5) * 8 + q;
    int n = ch * 32 + (l & 31);
    float v = 0.f;
    if (kg < 8192) v = ew2[kg * 64 + n];          // ew2 flat == W2flat[kg][n]
    else if (kg < 8256) v = eb2[(kg - 8192) * 64 + n];
    w2hp[idx] = (f16)v;
}

// ---------------- K3b: GRU weights -> f16, gate-col permuted, [192][64] ----------------
__global__ void k_prep_gru2(const float* __restrict__ wih, const float* __restrict__ whh,
                            f16* __restrict__ B1, f16* __restrict__ B2) {
    int idx = blockIdx.x * 256 + threadIdx.x;
    if (idx >= 12288) return;
    int cp = idx >> 6, k = idx & 63;
    int w = cp / 48, rem = cp % 48;
    int tg = rem >> 4, cc = rem & 15;
    int orow = tg * 64 + w * 16 + cc;
    B1[idx] = (f16)wih[orow * 64 + k];
    B2[idx] = (f16)whh[orow * 64 + k];
}

// ---------------- K3c: generic small f32 transpose (LSTM weights) ----------------
__global__ void k_transpose_f32(const float* __restrict__ in, float* __restrict__ outp,
                                int rows, int cols) {
    int idx = blockIdx.x * 256 + threadIdx.x;
    if (idx >= rows * cols) return;
    int r = idx / cols, c = idx - r * cols;
    outp[c * rows + r] = in[idx];
}

// ---------------- padded indices + degree count (merged) ----------------
__global__ void k_prep_idx(const int* __restrict__ src, const int* __restrict__ dst,
                           int* __restrict__ srcP, int* __restrict__ dstP, int* __restrict__ cnt) {
    int e = blockIdx.x * 256 + threadIdx.x;
    if (e >= EPAD) return;
    if (e < NEDGE) {
        int d = dst[e];
        srcP[e] = src[e];
        dstP[e] = d;
        atomicAdd(&cnt[d], 1);
    } else {
        srcP[e] = 0;
        dstP[e] = -1;
    }
}
__global__ void k_deg_inv(const int* __restrict__ cnt, float* __restrict__ dinv) {
    int n = blockIdx.x * 256 + threadIdx.x;
    if (n < NNODE) dinv[n] = 1.f / (float)max(cnt[n], 1);
}

// ---------------- K6: fused msg + scatter, LDS-free, 32x32x16 MFMA ----------------
// One wave/block; wave = 64 edges x 32 cols (2 M-tiles of 32, ch = column half).
// B double-buffered in regs (L2-hot 1MB stream); u depth-4 prefetch (f16x8 = 4 chunks).
#define MSG_STEP(BCUR, BNXT, CC)                                                                   \
    {                                                                                              \
        const f16x8* bp = gBp + (size_t)(g4 + (CC) + 1) * 1024;                                    \
        _Pragma("unroll") for (int ks = 0; ks < 8; ks++) BNXT[ks] = bp[ks * 64];                   \
        _Pragma("unroll") for (int ks = 0; ks < 8; ks++) {                                         \
            f16 uu0 = uc0[((CC) << 1) | (ks >> 2)];                                                \
            f16 uu1 = uc1[((CC) << 1) | (ks >> 2)];                                                \
            f16x8 av0 = xf[0][ks & 3] * uu0;                                                       \
            f16x8 av1 = xf[1][ks & 3] * uu1;                                                       \
            acc0 = __builtin_amdgcn_mfma_f32_32x32x16_f16(av0, BCUR[ks], acc0, 0, 0, 0);           \
            acc1 = __builtin_amdgcn_mfma_f32_32x32x16_f16(av1, BCUR[ks], acc1, 0, 0, 0);           \
        }                                                                                          \
    }

__global__ __launch_bounds__(64, 3) void k_msg_fused(
    const float* __restrict__ h, const f16* __restrict__ uE, const f16* __restrict__ w2hp,
    const int* __restrict__ srcP, const int* __restrict__ dstP, float* __restrict__ agg) {
    int l = threadIdx.x;
    int wid = blockIdx.x;
    int eb = (wid >> 1) * 64;  // edge base
    int ch = wid & 1;          // column half (32 cols)
    int lm = l & 31, hi = l >> 5;
    // A-side x fragments: xf[i][h4][q] = f16(h[src[eb+i*32+lm]][h4*16 + hi*8 + q])
    f16x8 xf[2][4];
#pragma unroll
    for (int i = 0; i < 2; i++) {
        const float* xb = h + (size_t)srcP[eb + i * 32 + lm] * 64;
#pragma unroll
        for (int h4 = 0; h4 < 4; h4++) {
            float4 v0 = *(const float4*)(xb + h4 * 16 + hi * 8);
            float4 v1 = *(const float4*)(xb + h4 * 16 + hi * 8 + 4);
            f16x8 xv;
            xv[0] = (f16)v0.x; xv[1] = (f16)v0.y; xv[2] = (f16)v0.z; xv[3] = (f16)v0.w;
            xv[4] = (f16)v1.x; xv[5] = (f16)v1.y; xv[6] = (f16)v1.z; xv[7] = (f16)v1.w;
            xf[i][h4] = xv;
        }
    }
    const f16x8* gBp = (const f16x8*)w2hp + ch * 512 + l;
    const f16x8* u0p = (const f16x8*)(uE + (size_t)(eb + lm) * 128);
    const f16x8* u1p = (const f16x8*)(uE + (size_t)(eb + 32 + lm) * 128);
    f32x16 acc0, acc1;
#pragma unroll
    for (int r = 0; r < 16; r++) { acc0[r] = 0.f; acc1[r] = 0.f; }
    f16x8 bA[8], bB[8];
#pragma unroll
    for (int ks = 0; ks < 8; ks++) bA[ks] = gBp[ks * 64];  // chunk 0 -> bA
    f16x8 uc0 = u0p[0], uc1 = u1p[0];
#pragma unroll 1
    for (int g = 0; g < 16; g++) {
        int g4 = g * 4;
        int gn = (g < 15) ? g + 1 : 15;
        f16x8 un0 = u0p[gn], un1 = u1p[gn];  // next u group (4 chunks ahead)
        MSG_STEP(bA, bB, 0)
        MSG_STEP(bB, bA, 1)
        MSG_STEP(bA, bB, 2)
        MSG_STEP(bB, bA, 3)   // final iter prefetches chunk 64 (bias rows) into bA
        uc0 = un0; uc1 = un1;
    }
    // bias chunk: u == 1, rows 8192..8255 of W2ext (ks 0..3); ks 4..7 are zeros
#pragma unroll
    for (int ks = 0; ks < 4; ks++) {
        acc0 = __builtin_amdgcn_mfma_f32_32x32x16_f16(xf[0][ks], bA[ks], acc0, 0, 0, 0);
        acc1 = __builtin_amdgcn_mfma_f32_32x32x16_f16(xf[1][ks], bA[ks], acc1, 0, 0, 0);
    }
    // scatter: C layout col = lane&31, row = (reg&3) + 8*(reg>>2) + 4*(lane>>5)
#pragma unroll
    for (int i = 0; i < 2; i++) {
        int rbase = eb + i * 32 + 4 * hi;
#pragma unroll
        for (int b = 0; b < 4; b++) {
            int4 d4 = *(const int4*)(dstP + rbase + 8 * b);
#pragma unroll
            for (int rr = 0; rr < 4; rr++) {
                int d = (rr == 0) ? d4.x : (rr == 1) ? d4.y : (rr == 2) ? d4.z : d4.w;
                float v = (i == 0) ? acc0[b * 4 + rr] : acc1[b * 4 + rr];
                if (d >= 0) atomicAdd(agg + (size_t)d * 64 + ch * 32 + lm, v);
            }
        }
    }
}

// ---------------- K7: GRU via MFMA, 64 nodes/block; zeroes agg for next iteration --------
#define GWP 72
__global__ __launch_bounds__(256) void k_gru2(float* __restrict__ agg,
                                              const float* __restrict__ dinv,
                                              const float* __restrict__ convb,
                                              const f16* __restrict__ B1g,
                                              const f16* __restrict__ B2g,
                                              const float* __restrict__ bih,
                                              const float* __restrict__ bhh,
                                              float* __restrict__ h) {
    __shared__ f16 sM[64 * GWP];
    __shared__ f16 sH[64 * GWP];
    int t = threadIdx.x;
    int nb = blockIdx.x * 64;
    int w = t >> 6, l = t & 63, lr = l & 15, lg = l >> 4;
    // B fragments straight from global (48KB, L1/L2-hot across blocks)
    f16x8 b1[2][3], b2[2][3];
#pragma unroll
    for (int kk = 0; kk < 2; kk++)
#pragma unroll
        for (int j = 0; j < 3; j++) {
            size_t off = (size_t)(w * 48 + j * 16 + lr) * 64 + kk * 32 + lg * 8;
            b1[kk][j] = *(const f16x8*)(B1g + off);
            b2[kk][j] = *(const f16x8*)(B2g + off);
        }
#pragma unroll
    for (int it = 0; it < 16; it++) {
        int idx = t + 256 * it;
        int node = idx >> 6, k = idx & 63;
        int gn = nb + node;
        float mv = 0.f, hv = 0.f;
        if (gn < NNODE) {
            size_t off = (size_t)gn * 64 + k;
            mv = fmaxf(agg[off] * dinv[gn] + convb[k], 0.f);
            hv = h[off];
            agg[off] = 0.f;  // reset for next msg pass
        }
        sM[node * GWP + k] = (f16)mv;
        sH[node * GWP + k] = (f16)hv;
    }
    __syncthreads();
    f32x4 aih[4][3], ahh[4][3];
#pragma unroll
    for (int i = 0; i < 4; i++)
#pragma unroll
        for (int j = 0; j < 3; j++) {
            aih[i][j] = (f32x4){0.f, 0.f, 0.f, 0.f};
            ahh[i][j] = (f32x4){0.f, 0.f, 0.f, 0.f};
        }
#pragma unroll
    for (int kk = 0; kk < 2; kk++) {
        f16x8 am[4], ah[4];
#pragma unroll
        for (int i = 0; i < 4; i++) {
            am[i] = *(const f16x8*)(sM + (i * 16 + lr) * GWP + kk * 32 + lg * 8);
            ah[i] = *(const f16x8*)(sH + (i * 16 + lr) * GWP + kk * 32 + lg * 8);
        }
#pragma unroll
        for (int i = 0; i < 4; i++)
#pragma unroll
            for (int j = 0; j < 3; j++) {
                aih[i][j] = __builtin_amdgcn_mfma_f32_16x16x32_f16(am[i], b1[kk][j], aih[i][j], 0, 0, 0);
                ahh[i][j] = __builtin_amdgcn_mfma_f32_16x16x32_f16(ah[i], b2[kk][j], ahh[i][j], 0, 0, 0);
            }
    }
    float bi0 = bih[0 * 64 + w * 16 + lr], bh0 = bhh[0 * 64 + w * 16 + lr];
    float bi1 = bih[1 * 64 + w * 16 + lr], bh1 = bhh[1 * 64 + w * 16 + lr];
    float bi2 = bih[2 * 64 + w * 16 + lr], bh2 = bhh[2 * 64 + w * 16 + lr];
#pragma unroll
    for (int i = 0; i < 4; i++)
#pragma unroll
        for (int r = 0; r < 4; r++) {
            int node = i * 16 + lg * 4 + r;
            int gn = nb + node;
            if (gn >= NNODE) continue;
            float rg = sigmoidf_(aih[i][0][r] + bi0 + ahh[i][0][r] + bh0);
            float z = sigmoidf_(aih[i][1][r] + bi1 + ahh[i][1][r] + bh1);
            float nn = tanhf(aih[i][2][r] + bi2 + rg * (ahh[i][2][r] + bh2));
            size_t off = (size_t)gn * 64 + w * 16 + lr;
            float hold = h[off];
            h[off] = (1.f - z) * nn + z * hold;
        }
}

// ---------------- K8: fused Set2Set (3x LSTM + attention) + final MLP, block per graph ----
#define FP 68
__global__ __launch_bounds__(256) void k_s2s(const float* __restrict__ feat,
                                             const float* __restrict__ wihT,
                                             const float* __restrict__ whhT,
                                             const float* __restrict__ lbih,
                                             const float* __restrict__ lbhh,
                                             const float* __restrict__ fc1w,
                                             const float* __restrict__ fc1b,
                                             const float* __restrict__ fc2w,
                                             const float* __restrict__ fc2b,
                                             float* __restrict__ out) {
    __shared__ float sf[NPG * FP];
    __shared__ float sq[128];   // q_star = [q, readout]
    __shared__ float sh[64], scc[64];
    __shared__ float sg[256];
    __shared__ float se[NPG];
    __shared__ float red[2];
    int g = blockIdx.x, t = threadIdx.x;
    const float* fb = feat + (size_t)g * NPG * 64;
    for (int idx = t; idx < NPG * 64; idx += 256)
        sf[(idx >> 6) * FP + (idx & 63)] = fb[idx];
    if (t < 128) sq[t] = 0.f;
    if (t >= 128 && t < 192) { sh[t - 128] = 0.f; scc[t - 128] = 0.f; }
    __syncthreads();
    for (int it = 0; it < 3; it++) {
        float gate = lbih[t] + lbhh[t];
#pragma unroll 8
        for (int i = 0; i < 128; i++) gate += sq[i] * wihT[i * 256 + t];
#pragma unroll 8
        for (int i = 0; i < 64; i++) gate += sh[i] * whhT[i * 256 + t];
        sg[t] = gate;
        __syncthreads();
        if (t < 64) {
            float ig = sigmoidf_(sg[t]);
            float fg = sigmoidf_(sg[64 + t]);
            float gg = tanhf(sg[128 + t]);
            float og = sigmoidf_(sg[192 + t]);
            float c = fg * scc[t] + ig * gg;
            scc[t] = c;
            float hv = og * tanhf(c);
            sh[t] = hv;
            sq[t] = hv;
        }
        __syncthreads();
        if (t < NPG) {
            float e = 0.f;
#pragma unroll 8
            for (int o = 0; o < 64; o++) e += sf[t * FP + o] * sh[o];
            se[t] = e;
        }
        __syncthreads();
        if (t < 64) {
            float m = -1e30f;
            for (int i2 = t; i2 < NPG; i2 += 64) m = fmaxf(m, se[i2]);
            for (int d = 32; d; d >>= 1) m = fmaxf(m, __shfl_down(m, d));
            if (t == 0) red[0] = m;
        }
        __syncthreads();
        float emax = red[0];
        if (t < NPG) se[t] = __expf(se[t] - emax);
        __syncthreads();
        if (t < 64) {
            float s = 0.f;
            for (int i2 = t; i2 < NPG; i2 += 64) s += se[i2];
            for (int d = 32; d; d >>= 1) s += __shfl_down(s, d);
            if (t == 0) red[1] = s;
        }
        __syncthreads();
        if (t < 64) {
            float dnv = 1.f / red[1];
            float r = 0.f;
#pragma unroll 4
            for (int n = 0; n < NPG; n++) r += se[n] * sf[n * FP + t];
            sq[64 + t] = r * dnv;
        }
        __syncthreads();
    }
    if (t < 64) {
        float hsum = fc1b[t];
#pragma unroll 8
        for (int i = 0; i < 128; i++) hsum += sq[i] * fc1w[i * 64 + t];
        float p = fmaxf(hsum, 0.f) * fc2w[t];
        for (int d = 32; d; d >>= 1) p += __shfl_down(p, d);
        if (t == 0) out[g] = p + fc2b[0];
    }
}

extern "C" void kernel_launch(void* const* d_in, const int* in_sizes, int n_in,
                              void* d_out, int out_size, void* d_ws, size_t ws_size,
                              hipStream_t stream) {
    const float* nfeat = (const float*)d_in[0];
    const float* efeat = (const float*)d_in[1];
    const float* lin0_w = (const float*)d_in[2];
    const float* lin0_b = (const float*)d_in[3];
    const float* ew1 = (const float*)d_in[4];
    const float* eb1 = (const float*)d_in[5];
    const float* ew2 = (const float*)d_in[6];
    const float* eb2 = (const float*)d_in[7];
    const float* convb = (const float*)d_in[8];
    const float* gwih = (const float*)d_in[9];
    const float* gwhh = (const float*)d_in[10];
    const float* gbih = (const float*)d_in[11];
    const float* gbhh = (const float*)d_in[12];
    const float* lwih = (const float*)d_in[13];
    const float* lwhh = (const float*)d_in[14];
    const float* lbih = (const float*)d_in[15];
    const float* lbhh = (const float*)d_in[16];
    const float* fc1w = (const float*)d_in[17];
    const float* fc1b = (const float*)d_in[18];
    const float* fc2w = (const float*)d_in[19];
    const float* fc2b = (const float*)d_in[20];
    const int* src = (const int*)d_in[21];
    const int* dst = (const int*)d_in[22];
    float* out = (float*)d_out;

    char* p = (char*)d_ws;
    auto alloc = [&](size_t bytes) {
        char* q = p;
        p += (bytes + 255) & ~(size_t)255;
        return q;
    };
    f16* uE = (f16*)alloc((size_t)EPAD * 128 * 2 + 256);    // 25.7 MB (+pad for tail group read)
    f16* w2hp = (f16*)alloc((size_t)540672 * 2);            // 1.08 MB
    float* h = (float*)alloc((size_t)NNODE * 64 * 4);       // 12.8 MB
    float* agg = (float*)alloc((size_t)NNODE * 64 * 4);     // 12.8 MB
    int* cnt = (int*)alloc((size_t)NNODE * 4);
    float* dinv = (float*)alloc((size_t)NNODE * 4);
    float* lwihT = (float*)alloc((size_t)128 * 256 * 4);
    float* lwhhT = (float*)alloc((size_t)64 * 256 * 4);
    f16* gB1 = (f16*)alloc((size_t)12288 * 2);
    f16* gB2 = (f16*)alloc((size_t)12288 * 2);
    int* srcP = (int*)alloc((size_t)EPAD * 4);
    int* dstP = (int*)alloc((size_t)EPAD * 4);
    if ((size_t)(p - (char*)d_ws) > ws_size) return;  // ~55 MB total

    hipMemsetAsync(cnt, 0, (size_t)NNODE * 4, stream);
    hipMemsetAsync(agg, 0, (size_t)NNODE * 64 * 4, stream);  // once; k_gru2 re-zeroes

    k_node_init<<<(NNODE * 64) / 256, 256, 0, stream>>>(nfeat, lin0_w, lin0_b, h);
    k_edge_mlp<<<(EPAD * 8) / 256, 256, 0, stream>>>(efeat, ew1, eb1, uE);
    k_pack_b<<<(540672 + 255) / 256, 256, 0, stream>>>(ew2, eb2, w2hp);
    k_prep_gru2<<<48, 256, 0, stream>>>(gwih, gwhh, gB1, gB2);
    k_transpose_f32<<<(256 * 128 + 255) / 256, 256, 0, stream>>>(lwih, lwihT, 256, 128);
    k_transpose_f32<<<(256 * 64 + 255) / 256, 256, 0, stream>>>(lwhh, lwhhT, 256, 64);
    k_prep_idx<<<EPAD / 256, 256, 0, stream>>>(src, dst, srcP, dstP, cnt);
    k_deg_inv<<<(NNODE + 255) / 256, 256, 0, stream>>>(cnt, dinv);

    for (int it = 0; it < 3; it++) {
        k_msg_fused<<<(EPAD / 64) * 2, 64, 0, stream>>>(h, uE, w2hp, srcP, dstP, agg);
        k_gru2<<<(NNODE + 63) / 64, 256, 0, stream>>>(agg, dinv, convb, gB1, gB2, gbih, gbhh, h);
    }
    k_s2s<<<NGR, 256, 0, stream>>>(h, lwihT, lwhhT, lbih, lbhh, fc1w, fc1b, fc2w, fc2b, out);
}

// Round 7
// 545.864 us; speedup vs baseline: 1.1619x; 1.0220x over previous
//
#include <hip/hip_runtime.h>

#define HD 64
#define NNODE 50000
#define NEDGE 100000
#define NGR 500
#define NPG 100      // nodes per graph (sorted, contiguous, equal size)
#define EPAD 100352  // 784 * 128
#define NCH 66       // B chunks of K=128 packed (0..63 data, 64 = bias rows, 65 zero)

typedef _Float16 f16;
typedef _Float16 f16x2 __attribute__((ext_vector_type(2)));
typedef _Float16 f16x8 __attribute__((ext_vector_type(8)));
typedef float f32x4 __attribute__((ext_vector_type(4)));
typedef float f32x16 __attribute__((ext_vector_type(16)));

__device__ __forceinline__ float sigmoidf_(float x) { return 1.f / (1.f + __expf(-x)); }

// ================= fused prep kernel: 7 sub-kernels dispatched by blockIdx range ==========
#define G_NODE 12500   // node_init: NNODE*64/256
#define G_EMLP 3136    // edge_mlp: EPAD*8/256
#define G_PACK 2112    // pack_b:   540672/256
#define G_GRU  48      // prep_gru2
#define G_T1   128     // lwih transpose 256x128
#define G_T2   64      // lwhh transpose 256x64
#define G_IDX  392     // prep_idx: EPAD/256
#define G_ALL (G_NODE + G_EMLP + G_PACK + G_GRU + G_T1 + G_T2 + G_IDX)

__global__ __launch_bounds__(256) void k_prep_all(
    const float* __restrict__ nfeat, const float* __restrict__ lin0_w, const float* __restrict__ lin0_b,
    const float* __restrict__ efeat, const float* __restrict__ ew1, const float* __restrict__ eb1,
    const float* __restrict__ ew2, const float* __restrict__ eb2,
    const float* __restrict__ gwih, const float* __restrict__ gwhh,
    const float* __restrict__ lwih, const float* __restrict__ lwhh,
    const int* __restrict__ src, const int* __restrict__ dst,
    float* __restrict__ h, f16* __restrict__ uE, f16* __restrict__ w2hp,
    f16* __restrict__ gB1, f16* __restrict__ gB2,
    float* __restrict__ lwihT, float* __restrict__ lwhhT,
    int* __restrict__ srcP, int* __restrict__ dstP, int* __restrict__ cnt) {
    int bb = blockIdx.x;
    int t = threadIdx.x;
    if (bb < G_NODE) {  // ---- node_init ----
        int idx = bb * 256 + t;
        int n = idx >> 6, o = idx & 63;
        if (n >= NNODE) return;
        const float* nf = nfeat + n * 32;
        float acc = lin0_b[o];
#pragma unroll
        for (int i = 0; i < 32; i++) acc += nf[i] * lin0_w[i * 64 + o];
        h[idx] = fmaxf(acc, 0.f);
        return;
    }
    bb -= G_NODE;
    if (bb < G_EMLP) {  // ---- edge_mlp: uE[e][0:128] = f16(relu(efeat@ew1+eb1)) ----
        __shared__ float sw[5 * 128];
        __shared__ float sb[128];
        for (int idx = t; idx < 640; idx += 256) sw[idx] = ew1[idx];
        if (t < 128) sb[t] = eb1[t];
        __syncthreads();
        int idx = bb * 256 + t;
        int e = idx >> 3, grp = idx & 7;
        bool valid = e < NEDGE;
        float ef[5];
#pragma unroll
        for (int i = 0; i < 5; i++) ef[i] = valid ? efeat[e * 5 + i] : 0.f;
        f16x8 v0, v1;
#pragma unroll
        for (int s = 0; s < 8; s++) {
            int k = grp * 16 + s;
            float acc = sb[k];
#pragma unroll
            for (int i = 0; i < 5; i++) acc += ef[i] * sw[i * 128 + k];
            v0[s] = valid ? (f16)fmaxf(acc, 0.f) : (f16)0.f;
        }
#pragma unroll
        for (int s = 0; s < 8; s++) {
            int k = grp * 16 + 8 + s;
            float acc = sb[k];
#pragma unroll
            for (int i = 0; i < 5; i++) acc += ef[i] * sw[i * 128 + k];
            v1[s] = valid ? (f16)fmaxf(acc, 0.f) : (f16)0.f;
        }
        *(f16x8*)(uE + (size_t)e * 128 + grp * 16) = v0;
        *(f16x8*)(uE + (size_t)e * 128 + grp * 16 + 8) = v1;
        return;
    }
    bb -= G_EMLP;
    if (bb < G_PACK) {  // ---- pack W2ext into 32x32x16 B-frag order ----
        int idx = bb * 256 + t;
        int q = idx & 7;
        int F = idx >> 3;
        int l = F & 63;
        int ks = (F >> 6) & 7;
        int ch = (F >> 9) & 1;
        int c = F >> 10;
        int kg = c * 128 + ks * 16 + (l >> 5) * 8 + q;
        int n = ch * 32 + (l & 31);
        float v = 0.f;
        if (kg < 8192) v = ew2[kg * 64 + n];
        else if (kg < 8256) v = eb2[(kg - 8192) * 64 + n];
        w2hp[idx] = (f16)v;
        return;
    }
    bb -= G_PACK;
    if (bb < G_GRU) {  // ---- GRU weights -> f16, gate-col permuted ----
        int idx = bb * 256 + t;
        int cp = idx >> 6, k = idx & 63;
        int w = cp / 48, rem = cp % 48;
        int tg = rem >> 4, cc = rem & 15;
        int orow = tg * 64 + w * 16 + cc;
        gB1[idx] = (f16)gwih[orow * 64 + k];
        gB2[idx] = (f16)gwhh[orow * 64 + k];
        return;
    }
    bb -= G_GRU;
    if (bb < G_T1) {  // ---- lwih transpose (256x128 -> 128x256) ----
        int idx = bb * 256 + t;
        int r = idx >> 7, c = idx & 127;
        lwihT[c * 256 + r] = lwih[idx];
        return;
    }
    bb -= G_T1;
    if (bb < G_T2) {  // ---- lwhh transpose (256x64 -> 64x256) ----
        int idx = bb * 256 + t;
        int r = idx >> 6, c = idx & 63;
        lwhhT[c * 256 + r] = lwhh[idx];
        return;
    }
    bb -= G_T2;
    {  // ---- prep_idx + degree count ----
        int e = bb * 256 + t;
        if (e >= EPAD) return;
        if (e < NEDGE) {
            int d = dst[e];
            srcP[e] = src[e];
            dstP[e] = d;
            atomicAdd(&cnt[d], 1);
        } else {
            srcP[e] = 0;
            dstP[e] = -1;
        }
    }
}

__global__ void k_deg_inv(const int* __restrict__ cnt, float* __restrict__ dinv) {
    int n = blockIdx.x * 256 + threadIdx.x;
    if (n < NNODE) dinv[n] = 1.f / (float)max(cnt[n], 1);
}

// ---------------- K6: fused msg + scatter, LDS-free, 32x32x16, M_rep=4 ----------------
// One wave/block; wave = 128 edges x 32 cols. B double-buffered regs (L2-hot 1MB stream);
// u depth-4 prefetch (f16x8 = 4 chunks/load). B-demand = 1KB/(4*8.07cy) = 127 B/cy/CU.
#define MSG_STEP(BCUR, BNXT, CC)                                                                   \
    {                                                                                              \
        const f16x8* bp = gBp + (size_t)(g4 + (CC) + 1) * 1024;                                    \
        _Pragma("unroll") for (int ks = 0; ks < 8; ks++) BNXT[ks] = bp[ks * 64];                   \
        _Pragma("unroll") for (int ks = 0; ks < 8; ks++) {                                         \
            _Pragma("unroll") for (int i = 0; i < 4; i++) {                                        \
                f16 uu = uc[i][((CC) << 1) | (ks >> 2)];                                           \
                f16x8 av = xf[i][ks & 3] * uu;                                                     \
                acc[i] = __builtin_amdgcn_mfma_f32_32x32x16_f16(av, BCUR[ks], acc[i], 0, 0, 0);    \
            }                                                                                      \
        }                                                                                          \
    }

__global__ __launch_bounds__(64, 2) void k_msg_fused(
    const float* __restrict__ h, const f16* __restrict__ uE, const f16* __restrict__ w2hp,
    const int* __restrict__ srcP, const int* __restrict__ dstP, float* __restrict__ agg) {
    int l = threadIdx.x;
    int wid = blockIdx.x;
    int eb = (wid >> 1) * 128;  // edge base (128 edges per wave)
    int ch = wid & 1;           // column half (32 cols)
    int lm = l & 31, hi = l >> 5;
    // A-side x fragments: xf[i][h4][q] = f16(h[src[eb+i*32+lm]][h4*16 + hi*8 + q])
    f16x8 xf[4][4];
#pragma unroll
    for (int i = 0; i < 4; i++) {
        const float* xb = h + (size_t)srcP[eb + i * 32 + lm] * 64;
#pragma unroll
        for (int h4 = 0; h4 < 4; h4++) {
            float4 v0 = *(const float4*)(xb + h4 * 16 + hi * 8);
            float4 v1 = *(const float4*)(xb + h4 * 16 + hi * 8 + 4);
            f16x8 xv;
            xv[0] = (f16)v0.x; xv[1] = (f16)v0.y; xv[2] = (f16)v0.z; xv[3] = (f16)v0.w;
            xv[4] = (f16)v1.x; xv[5] = (f16)v1.y; xv[6] = (f16)v1.z; xv[7] = (f16)v1.w;
            xf[i][h4] = xv;
        }
    }
    const f16x8* gBp = (const f16x8*)w2hp + ch * 512 + l;
    const f16x8* up[4];
#pragma unroll
    for (int i = 0; i < 4; i++) up[i] = (const f16x8*)(uE + (size_t)(eb + i * 32 + lm) * 128);
    f32x16 acc[4];
#pragma unroll
    for (int i = 0; i < 4; i++)
#pragma unroll
        for (int r = 0; r < 16; r++) acc[i][r] = 0.f;
    f16x8 bA[8], bB[8];
#pragma unroll
    for (int ks = 0; ks < 8; ks++) bA[ks] = gBp[ks * 64];  // chunk 0 -> bA
    f16x8 uc[4], un[4];
#pragma unroll
    for (int i = 0; i < 4; i++) uc[i] = up[i][0];
#pragma unroll 1
    for (int g = 0; g < 16; g++) {
        int g4 = g * 4;
        int gn = (g < 15) ? g + 1 : 15;
#pragma unroll
        for (int i = 0; i < 4; i++) un[i] = up[i][gn];  // next u group (4 chunks ahead)
        MSG_STEP(bA, bB, 0)
        MSG_STEP(bB, bA, 1)
        MSG_STEP(bA, bB, 2)
        MSG_STEP(bB, bA, 3)   // final iter prefetches chunk 64 (bias rows) into bA
#pragma unroll
        for (int i = 0; i < 4; i++) uc[i] = un[i];
    }
    // bias chunk: u == 1, rows 8192..8255 of W2ext (ks 0..3); ks 4..7 are zeros
#pragma unroll
    for (int ks = 0; ks < 4; ks++)
#pragma unroll
        for (int i = 0; i < 4; i++)
            acc[i] = __builtin_amdgcn_mfma_f32_32x32x16_f16(xf[i][ks], bA[ks], acc[i], 0, 0, 0);
    // scatter: C layout col = lane&31, row = (reg&3) + 8*(reg>>2) + 4*(lane>>5)
#pragma unroll
    for (int i = 0; i < 4; i++) {
        int rbase = eb + i * 32 + 4 * hi;
#pragma unroll
        for (int b = 0; b < 4; b++) {
            int4 d4 = *(const int4*)(dstP + rbase + 8 * b);
#pragma unroll
            for (int rr = 0; rr < 4; rr++) {
                int d = (rr == 0) ? d4.x : (rr == 1) ? d4.y : (rr == 2) ? d4.z : d4.w;
                float v = acc[i][b * 4 + rr];
                if (d >= 0) atomicAdd(agg + (size_t)d * 64 + ch * 32 + lm, v);
            }
        }
    }
}

// ---------------- K7: GRU via MFMA, 64 nodes/block; zeroes agg for next iteration --------
#define GWP 72
__global__ __launch_bounds__(256) void k_gru2(float* __restrict__ agg,
                                              const float* __restrict__ dinv,
                                              const float* __restrict__ convb,
                                              const f16* __restrict__ B1g,
                                              const f16* __restrict__ B2g,
                                              const float* __restrict__ bih,
                                              const float* __restrict__ bhh,
                                              float* __restrict__ h) {
    __shared__ f16 sM[64 * GWP];
    __shared__ f16 sH[64 * GWP];
    int t = threadIdx.x;
    int nb = blockIdx.x * 64;
    int w = t >> 6, l = t & 63, lr = l & 15, lg = l >> 4;
    f16x8 b1[2][3], b2[2][3];
#pragma unroll
    for (int kk = 0; kk < 2; kk++)
#pragma unroll
        for (int j = 0; j < 3; j++) {
            size_t off = (size_t)(w * 48 + j * 16 + lr) * 64 + kk * 32 + lg * 8;
            b1[kk][j] = *(const f16x8*)(B1g + off);
            b2[kk][j] = *(const f16x8*)(B2g + off);
        }
#pragma unroll
    for (int it = 0; it < 16; it++) {
        int idx = t + 256 * it;
        int node = idx >> 6, k = idx & 63;
        int gn = nb + node;
        float mv = 0.f, hv = 0.f;
        if (gn < NNODE) {
            size_t off = (size_t)gn * 64 + k;
            mv = fmaxf(agg[off] * dinv[gn] + convb[k], 0.f);
            hv = h[off];
            agg[off] = 0.f;  // reset for next msg pass
        }
        sM[node * GWP + k] = (f16)mv;
        sH[node * GWP + k] = (f16)hv;
    }
    __syncthreads();
    f32x4 aih[4][3], ahh[4][3];
#pragma unroll
    for (int i = 0; i < 4; i++)
#pragma unroll
        for (int j = 0; j < 3; j++) {
            aih[i][j] = (f32x4){0.f, 0.f, 0.f, 0.f};
            ahh[i][j] = (f32x4){0.f, 0.f, 0.f, 0.f};
        }
#pragma unroll
    for (int kk = 0; kk < 2; kk++) {
        f16x8 am[4], ah[4];
#pragma unroll
        for (int i = 0; i < 4; i++) {
            am[i] = *(const f16x8*)(sM + (i * 16 + lr) * GWP + kk * 32 + lg * 8);
            ah[i] = *(const f16x8*)(sH + (i * 16 + lr) * GWP + kk * 32 + lg * 8);
        }
#pragma unroll
        for (int i = 0; i < 4; i++)
#pragma unroll
            for (int j = 0; j < 3; j++) {
                aih[i][j] = __builtin_amdgcn_mfma_f32_16x16x32_f16(am[i], b1[kk][j], aih[i][j], 0, 0, 0);
                ahh[i][j] = __builtin_amdgcn_mfma_f32_16x16x32_f16(ah[i], b2[kk][j], ahh[i][j], 0, 0, 0);
            }
    }
    float bi0 = bih[0 * 64 + w * 16 + lr], bh0 = bhh[0 * 64 + w * 16 + lr];
    float bi1 = bih[1 * 64 + w * 16 + lr], bh1 = bhh[1 * 64 + w * 16 + lr];
    float bi2 = bih[2 * 64 + w * 16 + lr], bh2 = bhh[2 * 64 + w * 16 + lr];
#pragma unroll
    for (int i = 0; i < 4; i++)
#pragma unroll
        for (int r = 0; r < 4; r++) {
            int node = i * 16 + lg * 4 + r;
            int gn = nb + node;
            if (gn >= NNODE) continue;
            float rg = sigmoidf_(aih[i][0][r] + bi0 + ahh[i][0][r] + bh0);
            float z = sigmoidf_(aih[i][1][r] + bi1 + ahh[i][1][r] + bh1);
            float nn = tanhf(aih[i][2][r] + bi2 + rg * (ahh[i][2][r] + bh2));
            size_t off = (size_t)gn * 64 + w * 16 + lr;
            float hold = h[off];
            h[off] = (1.f - z) * nn + z * hold;
        }
}

// ---------------- K8: fused Set2Set (3x LSTM + attention) + final MLP, block per graph ----
#define FP 68
__global__ __launch_bounds__(256) void k_s2s(const float* __restrict__ feat,
                                             const float* __restrict__ wihT,
                                             const float* __restrict__ whhT,
                                             const float* __restrict__ lbih,
                                             const float* __restrict__ lbhh,
                                             const float* __restrict__ fc1w,
                                             const float* __restrict__ fc1b,
                                             const float* __restrict__ fc2w,
                                             const float* __restrict__ fc2b,
                                             float* __restrict__ out) {
    __shared__ float sf[NPG * FP];
    __shared__ float sq[128];
    __shared__ float sh[64], scc[64];
    __shared__ float sg[256];
    __shared__ float se[NPG];
    __shared__ float red[2];
    int g = blockIdx.x, t = threadIdx.x;
    const float* fb = feat + (size_t)g * NPG * 64;
    for (int idx = t; idx < NPG * 64; idx += 256)
        sf[(idx >> 6) * FP + (idx & 63)] = fb[idx];
    if (t < 128) sq[t] = 0.f;
    if (t >= 128 && t < 192) { sh[t - 128] = 0.f; scc[t - 128] = 0.f; }
    __syncthreads();
    for (int it = 0; it < 3; it++) {
        float gate = lbih[t] + lbhh[t];
#pragma unroll 8
        for (int i = 0; i < 128; i++) gate += sq[i] * wihT[i * 256 + t];
#pragma unroll 8
        for (int i = 0; i < 64; i++) gate += sh[i] * whhT[i * 256 + t];
        sg[t] = gate;
        __syncthreads();
        if (t < 64) {
            float ig = sigmoidf_(sg[t]);
            float fg = sigmoidf_(sg[64 + t]);
            float gg = tanhf(sg[128 + t]);
            float og = sigmoidf_(sg[192 + t]);
            float c = fg * scc[t] + ig * gg;
            scc[t] = c;
            float hv = og * tanhf(c);
            sh[t] = hv;
            sq[t] = hv;
        }
        __syncthreads();
        if (t < NPG) {
            float e = 0.f;
#pragma unroll 8
            for (int o = 0; o < 64; o++) e += sf[t * FP + o] * sh[o];
            se[t] = e;
        }
        __syncthreads();
        if (t < 64) {
            float m = -1e30f;
            for (int i2 = t; i2 < NPG; i2 += 64) m = fmaxf(m, se[i2]);
            for (int d = 32; d; d >>= 1) m = fmaxf(m, __shfl_down(m, d));
            if (t == 0) red[0] = m;
        }
        __syncthreads();
        float emax = red[0];
        if (t < NPG) se[t] = __expf(se[t] - emax);
        __syncthreads();
        if (t < 64) {
            float s = 0.f;
            for (int i2 = t; i2 < NPG; i2 += 64) s += se[i2];
            for (int d = 32; d; d >>= 1) s += __shfl_down(s, d);
            if (t == 0) red[1] = s;
        }
        __syncthreads();
        if (t < 64) {
            float dnv = 1.f / red[1];
            float r = 0.f;
#pragma unroll 4
            for (int n = 0; n < NPG; n++) r += se[n] * sf[n * FP + t];
            sq[64 + t] = r * dnv;
        }
        __syncthreads();
    }
    if (t < 64) {
        float hsum = fc1b[t];
#pragma unroll 8
        for (int i = 0; i < 128; i++) hsum += sq[i] * fc1w[i * 64 + t];
        float p = fmaxf(hsum, 0.f) * fc2w[t];
        for (int d = 32; d; d >>= 1) p += __shfl_down(p, d);
        if (t == 0) out[g] = p + fc2b[0];
    }
}

extern "C" void kernel_launch(void* const* d_in, const int* in_sizes, int n_in,
                              void* d_out, int out_size, void* d_ws, size_t ws_size,
                              hipStream_t stream) {
    const float* nfeat = (const float*)d_in[0];
    const float* efeat = (const float*)d_in[1];
    const float* lin0_w = (const float*)d_in[2];
    const float* lin0_b = (const float*)d_in[3];
    const float* ew1 = (const float*)d_in[4];
    const float* eb1 = (const float*)d_in[5];
    const float* ew2 = (const float*)d_in[6];
    const float* eb2 = (const float*)d_in[7];
    const float* convb = (const float*)d_in[8];
    const float* gwih = (const float*)d_in[9];
    const float* gwhh = (const float*)d_in[10];
    const float* gbih = (const float*)d_in[11];
    const float* gbhh = (const float*)d_in[12];
    const float* lwih = (const float*)d_in[13];
    const float* lwhh = (const float*)d_in[14];
    const float* lbih = (const float*)d_in[15];
    const float* lbhh = (const float*)d_in[16];
    const float* fc1w = (const float*)d_in[17];
    const float* fc1b = (const float*)d_in[18];
    const float* fc2w = (const float*)d_in[19];
    const float* fc2b = (const float*)d_in[20];
    const int* src = (const int*)d_in[21];
    const int* dst = (const int*)d_in[22];
    float* out = (float*)d_out;

    char* p = (char*)d_ws;
    auto alloc = [&](size_t bytes) {
        char* q = p;
        p += (bytes + 255) & ~(size_t)255;
        return q;
    };
    f16* uE = (f16*)alloc((size_t)EPAD * 128 * 2 + 256);    // 25.7 MB
    f16* w2hp = (f16*)alloc((size_t)540672 * 2);            // 1.08 MB
    float* h = (float*)alloc((size_t)NNODE * 64 * 4);       // 12.8 MB
    float* agg = (float*)alloc((size_t)NNODE * 64 * 4);     // 12.8 MB
    int* cnt = (int*)alloc((size_t)NNODE * 4);
    float* dinv = (float*)alloc((size_t)NNODE * 4);
    float* lwihT = (float*)alloc((size_t)128 * 256 * 4);
    float* lwhhT = (float*)alloc((size_t)64 * 256 * 4);
    f16* gB1 = (f16*)alloc((size_t)12288 * 2);
    f16* gB2 = (f16*)alloc((size_t)12288 * 2);
    int* srcP = (int*)alloc((size_t)EPAD * 4);
    int* dstP = (int*)alloc((size_t)EPAD * 4);
    if ((size_t)(p - (char*)d_ws) > ws_size) return;  // ~55 MB total

    hipMemsetAsync(cnt, 0, (size_t)NNODE * 4, stream);
    hipMemsetAsync(agg, 0, (size_t)NNODE * 64 * 4, stream);  // once; k_gru2 re-zeroes

    k_prep_all<<<G_ALL, 256, 0, stream>>>(nfeat, lin0_w, lin0_b, efeat, ew1, eb1, ew2, eb2,
                                          gwih, gwhh, lwih, lwhh, src, dst,
                                          h, uE, w2hp, gB1, gB2, lwihT, lwhhT, srcP, dstP, cnt);
    k_deg_inv<<<(NNODE + 255) / 256, 256, 0, stream>>>(cnt, dinv);

    for (int it = 0; it < 3; it++) {
        k_msg_fused<<<(EPAD / 128) * 2, 64, 0, stream>>>(h, uE, w2hp, srcP, dstP, agg);
        k_gru2<<<(NNODE + 63) / 64, 256, 0, stream>>>(agg, dinv, convb, gB1, gB2, gbih, gbhh, h);
    }
    k_s2s<<<NGR, 256, 0, stream>>>(h, lwihT, lwhhT, lbih, lbhh, fc1w, fc1b, fc2w, fc2b, out);
}